// Round 1
// 1150.170 us; speedup vs baseline: 1.3464x; 1.3464x over previous
//
#include <hip/hip_runtime.h>
#include <hip/hip_bf16.h>
#include <math.h>

typedef __hip_bfloat16 bf16;

#define NBATCH 4
#define NPTS   8192
#define TOTPTS 32768
#define DIM    128
#define DOUT   256
#define KNN    16

__device__ __forceinline__ float b2f(bf16 x) { return __bfloat162float(x); }
__device__ __forceinline__ bf16 f2b(float x) { return __float2bfloat16(x); }

__device__ __forceinline__ float rsum32(float v) {
#pragma unroll
  for (int o = 16; o; o >>= 1) v += __shfl_down(v, o, 32);
  return v;
}

// ---------------------------------------------------------------------------
// Pack xyz -> (x, y, z, |p|^2) float4 (one coalesced 16B load per candidate).
// ---------------------------------------------------------------------------
__global__ __launch_bounds__(256) void pack_kernel(const float* __restrict__ xyz,
                                                   float4* __restrict__ xyzw) {
  const int p = blockIdx.x * 256 + threadIdx.x;
  const float x = xyz[3 * p], y = xyz[3 * p + 1], z = xyz[3 * p + 2];
  xyzw[p] = make_float4(x, y, z, x * x + y * y + z * z);
}

// ---------------------------------------------------------------------------
// KNN v2: one wave per query, lane = candidate. The sorted top-16 list is
// DISTRIBUTED across lanes 0..15 (one slot per lane) instead of replicated
// in every lane's registers. An insert is now ~12 instructions (readlane
// broadcast + shfl_up shift + 2 cndmask pairs + readlane threshold) instead
// of a 16-step positional insert (~105 VALU inst) executed redundantly by
// all 64 lanes. Ascending candidate order + (bd <= dl) keep-condition
// preserves stable jax.lax.top_k tie semantics exactly as before.
// ---------------------------------------------------------------------------
__global__ __launch_bounds__(256) void knn_wave_kernel(
    const float4* __restrict__ xyzw, unsigned short* __restrict__ knn_out) {
  const int wid  = threadIdx.x >> 6;
  const int lane = threadIdx.x & 63;
  const int q = blockIdx.x * 4 + wid;     // wave-uniform query id
  const int b = q >> 13;
  const float4 me = xyzw[q];
  const float qx = me.x, qy = me.y, qz = me.z, qs = me.w;
  const float4* cb = xyzw + (size_t)b * NPTS;

  // lane l (l<16) holds slot l of the ascending-sorted top-16
  float bd = INFINITY;
  int   bi = 0x7fff;
  float tmax = INFINITY;                  // = slot 15 distance (wave-uniform)

  for (int g = 0; g < NPTS; g += 64) {
    const float4 t = cb[g + lane];
    const float d2 = qs + t.w - 2.f * (qx * t.x + qy * t.y + qz * t.z);
    unsigned long long mask = __ballot(d2 < tmax);
    while (mask) {                        // wave-uniform loop
      const int l = __builtin_ctzll(mask);
      mask &= mask - 1;
      const float dl = __int_as_float(
          __builtin_amdgcn_readlane(__float_as_int(d2), l));
      if (dl < tmax) {                    // re-check against shrunk threshold
        const int il = g + l;
        const bool keep = bd <= dl;       // ties: earlier index stays left
        const float pd = __shfl_up(bd, 1, 64);
        const int   pi = __shfl_up(bi, 1, 64);
        const bool fromPrev = (lane > 0) && (pd > dl);
        bd = keep ? bd : (fromPrev ? pd : dl);
        bi = keep ? bi : (fromPrev ? pi : il);
        tmax = __int_as_float(
            __builtin_amdgcn_readlane(__float_as_int(bd), 15));
      }
    }
  }
  if (lane < 16)
    knn_out[(size_t)q * KNN + lane] = (unsigned short)bi;
}

// ---------------------------------------------------------------------------
// Projections: per 8 rows compute LN1(features), then Q=f@Wq+bq, Kf=f@Wk+bk,
// Vf=f@Wv+bv (bf16 -> ws) and skip=LN1@Wq+bq (f32 -> d_out out-region).
// ---------------------------------------------------------------------------
__global__ __launch_bounds__(256) void proj_kernel(
    const float* __restrict__ feat,
    const float* __restrict__ Wq, const float* __restrict__ bq,
    const float* __restrict__ Wk, const float* __restrict__ bk,
    const float* __restrict__ Wv, const float* __restrict__ bv,
    const float* __restrict__ g1, const float* __restrict__ b1,
    bf16* __restrict__ Q, bf16* __restrict__ Kf, bf16* __restrict__ Vf,
    float* __restrict__ skip) {
  __shared__ float f[8][DIM];
  __shared__ float ln[8][DIM];
  __shared__ float mu8[8], rs8[8];
  const int tid = threadIdx.x;
  const size_t r0 = (size_t)blockIdx.x * 8;
  const float* src = feat + r0 * DIM;
#pragma unroll
  for (int i = 0; i < 4; i++) {
    const int idx = tid + i * 256;
    f[idx >> 7][idx & 127] = src[idx];
  }
  __syncthreads();
  const int r = tid >> 5, j = tid & 31;
  const float a0 = f[r][j], a1 = f[r][j + 32], a2 = f[r][j + 64], a3 = f[r][j + 96];
  float s = rsum32(a0 + a1 + a2 + a3);
  if (!j) mu8[r] = s * (1.f / 128.f);
  __syncthreads();
  const float mu = mu8[r];
  const float d0 = a0 - mu, d1 = a1 - mu, d2 = a2 - mu, d3 = a3 - mu;
  float ss = rsum32(d0 * d0 + d1 * d1 + d2 * d2 + d3 * d3);
  if (!j) rs8[r] = rsqrtf(ss * (1.f / 128.f) + 1e-5f);
  __syncthreads();
  const float rsd = rs8[r];
  ln[r][j]      = d0 * rsd * g1[j]      + b1[j];
  ln[r][j + 32] = d1 * rsd * g1[j + 32] + b1[j + 32];
  ln[r][j + 64] = d2 * rsd * g1[j + 64] + b1[j + 64];
  ln[r][j + 96] = d3 * rsd * g1[j + 96] + b1[j + 96];
  __syncthreads();
  float qa[8] = {}, ka[8] = {}, va[8] = {}, sa[8] = {};
  for (int d = 0; d < DIM; d += 4) {
    const float wq0 = Wq[(d + 0) * DOUT + tid], wq1 = Wq[(d + 1) * DOUT + tid];
    const float wq2 = Wq[(d + 2) * DOUT + tid], wq3 = Wq[(d + 3) * DOUT + tid];
    const float wk0 = Wk[(d + 0) * DOUT + tid], wk1 = Wk[(d + 1) * DOUT + tid];
    const float wk2 = Wk[(d + 2) * DOUT + tid], wk3 = Wk[(d + 3) * DOUT + tid];
    const float wv0 = Wv[(d + 0) * DOUT + tid], wv1 = Wv[(d + 1) * DOUT + tid];
    const float wv2 = Wv[(d + 2) * DOUT + tid], wv3 = Wv[(d + 3) * DOUT + tid];
#pragma unroll
    for (int rr = 0; rr < 8; rr++) {
      const float4 fv = *(const float4*)&f[rr][d];
      const float4 lv = *(const float4*)&ln[rr][d];
      qa[rr] += fv.x * wq0 + fv.y * wq1 + fv.z * wq2 + fv.w * wq3;
      ka[rr] += fv.x * wk0 + fv.y * wk1 + fv.z * wk2 + fv.w * wk3;
      va[rr] += fv.x * wv0 + fv.y * wv1 + fv.z * wv2 + fv.w * wv3;
      sa[rr] += lv.x * wq0 + lv.y * wq1 + lv.z * wq2 + lv.w * wq3;
    }
  }
  const float bqv = bq[tid], bkv = bk[tid], bvv = bv[tid];
#pragma unroll
  for (int rr = 0; rr < 8; rr++) {
    const size_t o = (r0 + rr) * DOUT + tid;
    Q[o]    = f2b(qa[rr] + bqv);
    Kf[o]   = f2b(ka[rr] + bkv);
    Vf[o]   = f2b(va[rr] + bvv);
    skip[o] = sa[rr] + bqv;
  }
}

// ---------------------------------------------------------------------------
// Attention v2: one block per point, wave = head, lane = dim. K/V gathered
// straight into REGISTERS (thread tid only ever needs element tid of each
// row — r8 insight), logits via per-lane partials + 16-accumulator
// __shfl_xor butterfly (every lane ends with all 16 logits -> softmax is
// lane-redundant, barrier-free), pos-MLP via shuffle-broadcast of h1 with
// one shared Wp2 load per j (no 512-LDS-read chains, no kfs/vfs LDS, no
// bank conflicts). 3 barriers total; LDS ~4.5 KB (was 43 KB).
// ---------------------------------------------------------------------------
__global__ __launch_bounds__(256) void attn_kernel(
    const float* __restrict__ xyz, const unsigned short* __restrict__ knn_in,
    bf16* __restrict__ QOA, const bf16* __restrict__ Kf, const bf16* __restrict__ Vf,
    const float* __restrict__ Wp1, const float* __restrict__ bp1,
    const float* __restrict__ Wp2, const float* __restrict__ bp2,
    float* __restrict__ AOUT) {
  __shared__ int   nidxS[16];
  __shared__ float relS[16][3];
  __shared__ float posS[16][65];
  const int tid  = threadIdx.x;
  const int w    = tid >> 6;        // wave id = head
  const int lane = tid & 63;        // lane = dim within head
  const int p = blockIdx.x;
  const int b = p >> 13, n = p & (NPTS - 1);

  if (tid < 16) nidxS[tid] = knn_in[(size_t)p * KNN + tid];
  const float qreg = b2f(QOA[(size_t)p * DOUT + tid]);   // own row, pre-write
  __syncthreads();                  // nidxS ready

  // K/V gather into registers (issued early; waitcnt lands before logits)
  float kreg[16], vreg[16];
  const size_t rowbase = (size_t)b * NPTS;
#pragma unroll
  for (int k = 0; k < 16; k++) {
    const size_t row = (rowbase + (size_t)nidxS[k]) * DOUT + tid;
    kreg[k] = b2f(Kf[row]);
    vreg[k] = b2f(Vf[row]);
  }
  // relative positions (wave 0 only -> barrier below)
  if (tid < 48) {
    const int k = tid / 3, c = tid - 3 * k;
    const float* xb = xyz + (size_t)b * NPTS * 3;
    relS[k][c] = xb[3 * nidxS[k] + c] - xb[3 * n + c];
  }
  __syncthreads();                  // relS ready

  // h1 = relu(rel @ Wp1 + bp1): wave w owns k = 4w+kk, lane holds dim
  const float w0 = Wp1[lane], w1 = Wp1[64 + lane], w2 = Wp1[128 + lane];
  const float bb1 = bp1[lane], bb2 = bp2[lane];
  float h1v[4];
#pragma unroll
  for (int kk = 0; kk < 4; kk++) {
    const int k = w * 4 + kk;
    h1v[kk] = fmaxf(bb1 + relS[k][0] * w0 + relS[k][1] * w1 + relS[k][2] * w2, 0.f);
  }
  // pos = h1 @ Wp2 + bp2 via shuffle-broadcast; one Wp2 load shared by 4 k's
  float acc[4] = {bb2, bb2, bb2, bb2};
#pragma unroll 8
  for (int j2 = 0; j2 < 64; j2++) {
    const float w2v = Wp2[j2 * 64 + lane];
#pragma unroll
    for (int kk = 0; kk < 4; kk++)
      acc[kk] += __shfl(h1v[kk], j2, 64) * w2v;
  }
#pragma unroll
  for (int kk = 0; kk < 4; kk++) posS[w * 4 + kk][lane] = acc[kk];
  __syncthreads();                  // posS ready

  // logits: per-lane partials, butterfly reduce -> all lanes hold all 16
  float posr[16], lg[16];
#pragma unroll
  for (int k = 0; k < 16; k++) {
    posr[k] = posS[k][lane];
    lg[k] = qreg * (kreg[k] + posr[k]);
  }
#pragma unroll
  for (int o = 32; o; o >>= 1) {
#pragma unroll
    for (int k = 0; k < 16; k++) lg[k] += __shfl_xor(lg[k], o, 64);
  }
  // softmax over k (lane-redundant, no sync)
  float m = -INFINITY;
#pragma unroll
  for (int k = 0; k < 16; k++) { lg[k] *= 0.125f; m = fmaxf(m, lg[k]); }
  float sum = 0.f;
#pragma unroll
  for (int k = 0; k < 16; k++) { lg[k] = expf(lg[k] - m); sum += lg[k]; }
  const float inv = 1.f / sum;
#pragma unroll
  for (int k = 0; k < 16; k++) lg[k] *= inv;
  // attn-weight store: lane l<16 writes a[l] (coalesced 64B per wave)
  float av = 0.f;
#pragma unroll
  for (int k = 0; k < 16; k++) if (lane == k) av = lg[k];
  if (lane < 16)
    AOUT[(((size_t)b * 4 + w) * NPTS + n) * KNN + lane] = av;
  // output: sum_k a[k] * (v[k] + pos[k][d]) -> overwrite own Q row
  float o = 0.f;
#pragma unroll
  for (int k = 0; k < 16; k++) o += lg[k] * (vreg[k] + posr[k]);
  QOA[(size_t)p * DOUT + tid] = f2b(o);
}

// ---------------------------------------------------------------------------
// FFN + LN2 + residual: per 8 rows: fc1=relu(x@Wf1+bf1), fc2=fc1@Wf2+bf2,
// out = LN2(fc2)*g2+b2 + skip. skip lives in d_out (f32; read, then
// overwritten by the same thread/element with the final f32 value).
// ---------------------------------------------------------------------------
__global__ __launch_bounds__(256) void ffn_kernel(
    const bf16* __restrict__ OA,
    const float* __restrict__ Wf1, const float* __restrict__ bf1,
    const float* __restrict__ Wf2, const float* __restrict__ bf2,
    const float* __restrict__ g2, const float* __restrict__ b2p,
    float* __restrict__ out) {
  __shared__ float x[8][DOUT];
  __shared__ float y[8][DOUT];
  __shared__ float mu8[8], rs8[8];
  const int tid = threadIdx.x;
  const size_t r0 = (size_t)blockIdx.x * 8;
  const bf16* src = OA + r0 * DOUT;
#pragma unroll
  for (int i = 0; i < 8; i++) x[i][tid] = b2f(src[i * DOUT + tid]);
  __syncthreads();
  float acc[8] = {};
  for (int d = 0; d < DOUT; d += 4) {
    const float w0 = Wf1[(d + 0) * DOUT + tid];
    const float w1 = Wf1[(d + 1) * DOUT + tid];
    const float w2 = Wf1[(d + 2) * DOUT + tid];
    const float w3 = Wf1[(d + 3) * DOUT + tid];
#pragma unroll
    for (int rr = 0; rr < 8; rr++) {
      const float4 v = *(const float4*)&x[rr][d];
      acc[rr] += v.x * w0 + v.y * w1 + v.z * w2 + v.w * w3;
    }
  }
  const float b1v = bf1[tid];
#pragma unroll
  for (int rr = 0; rr < 8; rr++) y[rr][tid] = fmaxf(acc[rr] + b1v, 0.f);
  __syncthreads();
  float acc2[8] = {};
  for (int d = 0; d < DOUT; d += 4) {
    const float w0 = Wf2[(d + 0) * DOUT + tid];
    const float w1 = Wf2[(d + 1) * DOUT + tid];
    const float w2 = Wf2[(d + 2) * DOUT + tid];
    const float w3 = Wf2[(d + 3) * DOUT + tid];
#pragma unroll
    for (int rr = 0; rr < 8; rr++) {
      const float4 v = *(const float4*)&y[rr][d];
      acc2[rr] += v.x * w0 + v.y * w1 + v.z * w2 + v.w * w3;
    }
  }
  const float b2v = bf2[tid];
#pragma unroll
  for (int rr = 0; rr < 8; rr++) x[rr][tid] = acc2[rr] + b2v;   // fc2 -> x
  __syncthreads();
  const int r = tid >> 5, j = tid & 31;
  float s = 0.f;
#pragma unroll
  for (int k2 = 0; k2 < 8; k2++) s += x[r][j + 32 * k2];
  s = rsum32(s);
  if (!j) mu8[r] = s * (1.f / 256.f);
  __syncthreads();
  const float mu = mu8[r];
  float ss = 0.f;
#pragma unroll
  for (int k2 = 0; k2 < 8; k2++) { const float dd = x[r][j + 32 * k2] - mu; ss += dd * dd; }
  ss = rsum32(ss);
  if (!j) rs8[r] = rsqrtf(ss * (1.f / 256.f) + 1e-5f);
  __syncthreads();
  const float gv = g2[tid], bbv = b2p[tid];
#pragma unroll
  for (int rr = 0; rr < 8; rr++) {
    const size_t o = (r0 + rr) * DOUT + tid;
    const float sk = out[o];        // skip stored here by proj_kernel (f32)
    out[o] = (x[rr][tid] - mu8[rr]) * rs8[rr] * gv + bbv + sk;
  }
}

extern "C" void kernel_launch(void* const* d_in, const int* in_sizes, int n_in,
                              void* d_out, int out_size, void* d_ws, size_t ws_size,
                              hipStream_t stream) {
  const float* xyz  = (const float*)d_in[0];
  const float* feat = (const float*)d_in[1];
  const float* Wq   = (const float*)d_in[2];
  const float* bq   = (const float*)d_in[3];
  const float* Wk   = (const float*)d_in[4];
  const float* bk   = (const float*)d_in[5];
  const float* Wv   = (const float*)d_in[6];
  const float* bv   = (const float*)d_in[7];
  const float* Wp1  = (const float*)d_in[8];
  const float* bp1  = (const float*)d_in[9];
  const float* Wp2  = (const float*)d_in[10];
  const float* bp2  = (const float*)d_in[11];
  const float* Wf1  = (const float*)d_in[12];
  const float* bf1  = (const float*)d_in[13];
  const float* Wf2  = (const float*)d_in[14];
  const float* bf2  = (const float*)d_in[15];
  const float* g1   = (const float*)d_in[16];
  const float* b1   = (const float*)d_in[17];
  const float* g2   = (const float*)d_in[18];
  const float* b2   = (const float*)d_in[19];

  float* out  = (float*)d_out;
  float* aout = out + (size_t)TOTPTS * DOUT;  // attn-weights output region (f32)

  // workspace layout (49 MB peak):
  //   [0, 1 MB)    final knn indices, uint16 (persists through attn)
  //   [1, 17 MB)   QOA bf16 (proj -> attn, aliased Q/out-rows)
  //   [17, 33 MB)  Kf bf16
  //   [26, 26.5)   phase: packed xyzw float4 (dead before proj writes Kf)
  //   [33, 49 MB)  Vf bf16
  unsigned short* knn  = (unsigned short*)d_ws;
  float4*         xyzw = (float4*)((char*)d_ws + (size_t)(26 << 20));
  bf16* QOA = (bf16*)((char*)d_ws + (size_t)(1 << 20));
  bf16* Kf  = QOA + (size_t)TOTPTS * DOUT;
  bf16* Vf  = Kf  + (size_t)TOTPTS * DOUT;

  pack_kernel<<<TOTPTS / 256, 256, 0, stream>>>(xyz, xyzw);
  knn_wave_kernel<<<TOTPTS / 4, 256, 0, stream>>>(xyzw, knn);
  proj_kernel<<<TOTPTS / 8, 256, 0, stream>>>(feat, Wq, bq, Wk, bk, Wv, bv, g1, b1,
                                              QOA, Kf, Vf, /*skip->*/out);
  attn_kernel<<<TOTPTS, 256, 0, stream>>>(xyz, knn, QOA, Kf, Vf, Wp1, bp1, Wp2, bp2,
                                          aout);
  ffn_kernel<<<TOTPTS / 8, 256, 0, stream>>>(QOA, Wf1, bf1, Wf2, bf2, g2, b2, out);
}

// Round 2
// 902.280 us; speedup vs baseline: 1.7163x; 1.2747x over previous
//
#include <hip/hip_runtime.h>
#include <hip/hip_bf16.h>
#include <math.h>

typedef __hip_bfloat16 bf16;

#define NBATCH 4
#define NPTS   8192
#define TOTPTS 32768
#define DIM    128
#define DOUT   256
#define KNN    16

__device__ __forceinline__ float b2f(bf16 x) { return __bfloat162float(x); }
__device__ __forceinline__ bf16 f2b(float x) { return __float2bfloat16(x); }

__device__ __forceinline__ float rsum32(float v) {
#pragma unroll
  for (int o = 16; o; o >>= 1) v += __shfl_down(v, o, 32);
  return v;
}

// ---------------------------------------------------------------------------
// Pack xyz -> (x, y, z, |p|^2) float4 (one coalesced 16B load per candidate).
// ---------------------------------------------------------------------------
__global__ __launch_bounds__(256) void pack_kernel(const float* __restrict__ xyz,
                                                   float4* __restrict__ xyzw) {
  const int p = blockIdx.x * 256 + threadIdx.x;
  const float x = xyz[3 * p], y = xyz[3 * p + 1], z = xyz[3 * p + 2];
  xyzw[p] = make_float4(x, y, z, x * x + y * y + z * z);
}

// ---------------------------------------------------------------------------
// KNN v2: one wave per query, lane = candidate; sorted top-16 distributed
// across lanes 0..15 (slot per lane). Insert = readlane broadcast + shfl_up
// shift + cndmask (~12 inst vs ~105 replicated). Ascending candidate order +
// (bd <= dl) keep-condition preserves stable jax.lax.top_k tie semantics.
// ---------------------------------------------------------------------------
__global__ __launch_bounds__(256) void knn_wave_kernel(
    const float4* __restrict__ xyzw, unsigned short* __restrict__ knn_out) {
  const int wid  = threadIdx.x >> 6;
  const int lane = threadIdx.x & 63;
  const int q = blockIdx.x * 4 + wid;     // wave-uniform query id
  const int b = q >> 13;
  const float4 me = xyzw[q];
  const float qx = me.x, qy = me.y, qz = me.z, qs = me.w;
  const float4* cb = xyzw + (size_t)b * NPTS;

  float bd = INFINITY;
  int   bi = 0x7fff;
  float tmax = INFINITY;                  // = slot 15 distance (wave-uniform)

  for (int g = 0; g < NPTS; g += 64) {
    const float4 t = cb[g + lane];
    const float d2 = qs + t.w - 2.f * (qx * t.x + qy * t.y + qz * t.z);
    unsigned long long mask = __ballot(d2 < tmax);
    while (mask) {                        // wave-uniform loop
      const int l = __builtin_ctzll(mask);
      mask &= mask - 1;
      const float dl = __int_as_float(
          __builtin_amdgcn_readlane(__float_as_int(d2), l));
      if (dl < tmax) {                    // re-check against shrunk threshold
        const int il = g + l;
        const bool keep = bd <= dl;       // ties: earlier index stays left
        const float pd = __shfl_up(bd, 1, 64);
        const int   pi = __shfl_up(bi, 1, 64);
        const bool fromPrev = (lane > 0) && (pd > dl);
        bd = keep ? bd : (fromPrev ? pd : dl);
        bi = keep ? bi : (fromPrev ? pi : il);
        tmax = __int_as_float(
            __builtin_amdgcn_readlane(__float_as_int(bd), 15));
      }
    }
  }
  if (lane < 16)
    knn_out[(size_t)q * KNN + lane] = (unsigned short)bi;
}

// ---------------------------------------------------------------------------
// pos_kernel (new, round 2): the pos-MLP hoisted out of attn. Wave = point;
// lane = j/output dim. h1 (16 k-rows x 64) staged in LDS, pos phase reads h1
// as wave-uniform broadcast ds_read_b128 (4 j's per op) so each Wp2 load is
// amortized over 16 rows (attn's shuffle-MLP amortized over only 4, and ran
// inside the latency-critical gather kernel). Runs BEFORE proj_kernel so the
// packed xyzw overlay (inside the future Kf region) is still alive.
// Output posG bf16[p][k][64] (head-independent).
// ---------------------------------------------------------------------------
__global__ __launch_bounds__(256) void pos_kernel(
    const float4* __restrict__ xyzw, const unsigned short* __restrict__ knn_in,
    const float* __restrict__ Wp1, const float* __restrict__ bp1,
    const float* __restrict__ Wp2, const float* __restrict__ bp2,
    bf16* __restrict__ posG) {
  __shared__ float h1S[4][16][64];        // 16 KB
  const int wid = threadIdx.x >> 6, lane = threadIdx.x & 63;
  const int p = blockIdx.x * 4 + wid;
  const int b = p >> 13, n = p & (NPTS - 1);
  const float4* cb = xyzw + (size_t)b * NPTS;
  const float4 me = cb[n];

  float rx = 0.f, ry = 0.f, rz = 0.f;
  if (lane < 16) {
    const int idx = knn_in[(size_t)p * KNN + lane];
    const float4 t = cb[idx];
    rx = t.x - me.x; ry = t.y - me.y; rz = t.z - me.z;
  }
  const float w0 = Wp1[lane], w1 = Wp1[64 + lane], w2 = Wp1[128 + lane];
  const float bb1 = bp1[lane], bb2 = bp2[lane];
#pragma unroll
  for (int k = 0; k < 16; k++) {
    const float r0 = __shfl(rx, k, 64);
    const float r1 = __shfl(ry, k, 64);
    const float r2 = __shfl(rz, k, 64);
    h1S[wid][k][lane] = fmaxf(bb1 + r0 * w0 + r1 * w1 + r2 * w2, 0.f);
  }
  __syncthreads();                        // cheap (4 waves); guards LDS RAW

  float acc[16];
#pragma unroll
  for (int k = 0; k < 16; k++) acc[k] = bb2;
  for (int jq = 0; jq < 16; jq++) {
    const float w2a = Wp2[(jq * 4 + 0) * 64 + lane];
    const float w2b = Wp2[(jq * 4 + 1) * 64 + lane];
    const float w2c = Wp2[(jq * 4 + 2) * 64 + lane];
    const float w2d = Wp2[(jq * 4 + 3) * 64 + lane];
#pragma unroll
    for (int k = 0; k < 16; k++) {
      const float4 h = *(const float4*)&h1S[wid][k][jq * 4];  // broadcast b128
      acc[k] += h.x * w2a + h.y * w2b + h.z * w2c + h.w * w2d;
    }
  }
#pragma unroll
  for (int k = 0; k < 16; k++)
    posG[((size_t)p * KNN + k) * 64 + lane] = f2b(acc[k]);
}

// ---------------------------------------------------------------------------
// Projections: per 8 rows compute LN1(features), then Q=f@Wq+bq, Kf=f@Wk+bk,
// Vf=f@Wv+bv (bf16 -> ws) and skip=LN1@Wq+bq (f32 -> d_out out-region).
// ---------------------------------------------------------------------------
__global__ __launch_bounds__(256) void proj_kernel(
    const float* __restrict__ feat,
    const float* __restrict__ Wq, const float* __restrict__ bq,
    const float* __restrict__ Wk, const float* __restrict__ bk,
    const float* __restrict__ Wv, const float* __restrict__ bv,
    const float* __restrict__ g1, const float* __restrict__ b1,
    bf16* __restrict__ Q, bf16* __restrict__ Kf, bf16* __restrict__ Vf,
    float* __restrict__ skip) {
  __shared__ float f[8][DIM];
  __shared__ float ln[8][DIM];
  __shared__ float mu8[8], rs8[8];
  const int tid = threadIdx.x;
  const size_t r0 = (size_t)blockIdx.x * 8;
  const float* src = feat + r0 * DIM;
#pragma unroll
  for (int i = 0; i < 4; i++) {
    const int idx = tid + i * 256;
    f[idx >> 7][idx & 127] = src[idx];
  }
  __syncthreads();
  const int r = tid >> 5, j = tid & 31;
  const float a0 = f[r][j], a1 = f[r][j + 32], a2 = f[r][j + 64], a3 = f[r][j + 96];
  float s = rsum32(a0 + a1 + a2 + a3);
  if (!j) mu8[r] = s * (1.f / 128.f);
  __syncthreads();
  const float mu = mu8[r];
  const float d0 = a0 - mu, d1 = a1 - mu, d2 = a2 - mu, d3 = a3 - mu;
  float ss = rsum32(d0 * d0 + d1 * d1 + d2 * d2 + d3 * d3);
  if (!j) rs8[r] = rsqrtf(ss * (1.f / 128.f) + 1e-5f);
  __syncthreads();
  const float rsd = rs8[r];
  ln[r][j]      = d0 * rsd * g1[j]      + b1[j];
  ln[r][j + 32] = d1 * rsd * g1[j + 32] + b1[j + 32];
  ln[r][j + 64] = d2 * rsd * g1[j + 64] + b1[j + 64];
  ln[r][j + 96] = d3 * rsd * g1[j + 96] + b1[j + 96];
  __syncthreads();
  float qa[8] = {}, ka[8] = {}, va[8] = {}, sa[8] = {};
  for (int d = 0; d < DIM; d += 4) {
    const float wq0 = Wq[(d + 0) * DOUT + tid], wq1 = Wq[(d + 1) * DOUT + tid];
    const float wq2 = Wq[(d + 2) * DOUT + tid], wq3 = Wq[(d + 3) * DOUT + tid];
    const float wk0 = Wk[(d + 0) * DOUT + tid], wk1 = Wk[(d + 1) * DOUT + tid];
    const float wk2 = Wk[(d + 2) * DOUT + tid], wk3 = Wk[(d + 3) * DOUT + tid];
    const float wv0 = Wv[(d + 0) * DOUT + tid], wv1 = Wv[(d + 1) * DOUT + tid];
    const float wv2 = Wv[(d + 2) * DOUT + tid], wv3 = Wv[(d + 3) * DOUT + tid];
#pragma unroll
    for (int rr = 0; rr < 8; rr++) {
      const float4 fv = *(const float4*)&f[rr][d];
      const float4 lv = *(const float4*)&ln[rr][d];
      qa[rr] += fv.x * wq0 + fv.y * wq1 + fv.z * wq2 + fv.w * wq3;
      ka[rr] += fv.x * wk0 + fv.y * wk1 + fv.z * wk2 + fv.w * wk3;
      va[rr] += fv.x * wv0 + fv.y * wv1 + fv.z * wv2 + fv.w * wv3;
      sa[rr] += lv.x * wq0 + lv.y * wq1 + lv.z * wq2 + lv.w * wq3;
    }
  }
  const float bqv = bq[tid], bkv = bk[tid], bvv = bv[tid];
#pragma unroll
  for (int rr = 0; rr < 8; rr++) {
    const size_t o = (r0 + rr) * DOUT + tid;
    Q[o]    = f2b(qa[rr] + bqv);
    Kf[o]   = f2b(ka[rr] + bkv);
    Vf[o]   = f2b(va[rr] + bvv);
    skip[o] = sa[rr] + bqv;
  }
}

// ---------------------------------------------------------------------------
// Attention v3: pos-MLP removed (precomputed posG, bf16). One block per
// point, wave = head, lane = dim. K/V gathered into registers, posr streamed
// coalesced. Logits via 16-accumulator __shfl_xor butterfly (lane-redundant
// softmax, barrier-free). 1 barrier total.
// ---------------------------------------------------------------------------
__global__ __launch_bounds__(256) void attn_kernel(
    const unsigned short* __restrict__ knn_in,
    bf16* __restrict__ QOA, const bf16* __restrict__ Kf, const bf16* __restrict__ Vf,
    const bf16* __restrict__ posG,
    float* __restrict__ AOUT) {
  __shared__ int nidxS[16];
  const int tid  = threadIdx.x;
  const int w    = tid >> 6;        // wave id = head
  const int lane = tid & 63;        // lane = dim within head
  const int p = blockIdx.x;
  const int b = p >> 13, n = p & (NPTS - 1);

  if (tid < 16) nidxS[tid] = knn_in[(size_t)p * KNN + tid];
  const float qreg = b2f(QOA[(size_t)p * DOUT + tid]);   // own row, pre-write
  __syncthreads();                  // nidxS ready

  // K/V gather + pos stream into registers
  float kreg[16], vreg[16], posr[16];
  const size_t rowbase = (size_t)b * NPTS;
  const bf16* pg = posG + (size_t)p * KNN * 64 + lane;
#pragma unroll
  for (int k = 0; k < 16; k++) {
    const size_t row = (rowbase + (size_t)nidxS[k]) * DOUT + tid;
    kreg[k] = b2f(Kf[row]);
    vreg[k] = b2f(Vf[row]);
    posr[k] = b2f(pg[k * 64]);
  }

  // logits: per-lane partials, butterfly reduce -> all lanes hold all 16
  float lg[16];
#pragma unroll
  for (int k = 0; k < 16; k++) lg[k] = qreg * (kreg[k] + posr[k]);
#pragma unroll
  for (int o = 32; o; o >>= 1) {
#pragma unroll
    for (int k = 0; k < 16; k++) lg[k] += __shfl_xor(lg[k], o, 64);
  }
  // softmax over k (lane-redundant, no sync)
  float m = -INFINITY;
#pragma unroll
  for (int k = 0; k < 16; k++) { lg[k] *= 0.125f; m = fmaxf(m, lg[k]); }
  float sum = 0.f;
#pragma unroll
  for (int k = 0; k < 16; k++) { lg[k] = expf(lg[k] - m); sum += lg[k]; }
  const float inv = 1.f / sum;
#pragma unroll
  for (int k = 0; k < 16; k++) lg[k] *= inv;
  // attn-weight store: lane l<16 writes a[l] (coalesced 64B per wave)
  float av = 0.f;
#pragma unroll
  for (int k = 0; k < 16; k++) if (lane == k) av = lg[k];
  if (lane < 16)
    AOUT[(((size_t)b * 4 + w) * NPTS + n) * KNN + lane] = av;
  // output: sum_k a[k] * (v[k] + pos[k][d]) -> overwrite own Q row
  float o = 0.f;
#pragma unroll
  for (int k = 0; k < 16; k++) o += lg[k] * (vreg[k] + posr[k]);
  QOA[(size_t)p * DOUT + tid] = f2b(o);
}

// ---------------------------------------------------------------------------
// FFN + LN2 + residual: per 8 rows: fc1=relu(x@Wf1+bf1), fc2=fc1@Wf2+bf2,
// out = LN2(fc2)*g2+b2 + skip. skip lives in d_out (f32; read, then
// overwritten by the same thread/element with the final f32 value).
// ---------------------------------------------------------------------------
__global__ __launch_bounds__(256) void ffn_kernel(
    const bf16* __restrict__ OA,
    const float* __restrict__ Wf1, const float* __restrict__ bf1,
    const float* __restrict__ Wf2, const float* __restrict__ bf2,
    const float* __restrict__ g2, const float* __restrict__ b2p,
    float* __restrict__ out) {
  __shared__ float x[8][DOUT];
  __shared__ float y[8][DOUT];
  __shared__ float mu8[8], rs8[8];
  const int tid = threadIdx.x;
  const size_t r0 = (size_t)blockIdx.x * 8;
  const bf16* src = OA + r0 * DOUT;
#pragma unroll
  for (int i = 0; i < 8; i++) x[i][tid] = b2f(src[i * DOUT + tid]);
  __syncthreads();
  float acc[8] = {};
  for (int d = 0; d < DOUT; d += 4) {
    const float w0 = Wf1[(d + 0) * DOUT + tid];
    const float w1 = Wf1[(d + 1) * DOUT + tid];
    const float w2 = Wf1[(d + 2) * DOUT + tid];
    const float w3 = Wf1[(d + 3) * DOUT + tid];
#pragma unroll
    for (int rr = 0; rr < 8; rr++) {
      const float4 v = *(const float4*)&x[rr][d];
      acc[rr] += v.x * w0 + v.y * w1 + v.z * w2 + v.w * w3;
    }
  }
  const float b1v = bf1[tid];
#pragma unroll
  for (int rr = 0; rr < 8; rr++) y[rr][tid] = fmaxf(acc[rr] + b1v, 0.f);
  __syncthreads();
  float acc2[8] = {};
  for (int d = 0; d < DOUT; d += 4) {
    const float w0 = Wf2[(d + 0) * DOUT + tid];
    const float w1 = Wf2[(d + 1) * DOUT + tid];
    const float w2 = Wf2[(d + 2) * DOUT + tid];
    const float w3 = Wf2[(d + 3) * DOUT + tid];
#pragma unroll
    for (int rr = 0; rr < 8; rr++) {
      const float4 v = *(const float4*)&y[rr][d];
      acc2[rr] += v.x * w0 + v.y * w1 + v.z * w2 + v.w * w3;
    }
  }
  const float b2v = bf2[tid];
#pragma unroll
  for (int rr = 0; rr < 8; rr++) x[rr][tid] = acc2[rr] + b2v;   // fc2 -> x
  __syncthreads();
  const int r = tid >> 5, j = tid & 31;
  float s = 0.f;
#pragma unroll
  for (int k2 = 0; k2 < 8; k2++) s += x[r][j + 32 * k2];
  s = rsum32(s);
  if (!j) mu8[r] = s * (1.f / 256.f);
  __syncthreads();
  const float mu = mu8[r];
  float ss = 0.f;
#pragma unroll
  for (int k2 = 0; k2 < 8; k2++) { const float dd = x[r][j + 32 * k2] - mu; ss += dd * dd; }
  ss = rsum32(ss);
  if (!j) rs8[r] = rsqrtf(ss * (1.f / 256.f) + 1e-5f);
  __syncthreads();
  const float gv = g2[tid], bbv = b2p[tid];
#pragma unroll
  for (int rr = 0; rr < 8; rr++) {
    const size_t o = (r0 + rr) * DOUT + tid;
    const float sk = out[o];        // skip stored here by proj_kernel (f32)
    out[o] = (x[rr][tid] - mu8[rr]) * rs8[rr] * gv + bbv + sk;
  }
}

extern "C" void kernel_launch(void* const* d_in, const int* in_sizes, int n_in,
                              void* d_out, int out_size, void* d_ws, size_t ws_size,
                              hipStream_t stream) {
  const float* xyz  = (const float*)d_in[0];
  const float* feat = (const float*)d_in[1];
  const float* Wq   = (const float*)d_in[2];
  const float* bq   = (const float*)d_in[3];
  const float* Wk   = (const float*)d_in[4];
  const float* bk   = (const float*)d_in[5];
  const float* Wv   = (const float*)d_in[6];
  const float* bv   = (const float*)d_in[7];
  const float* Wp1  = (const float*)d_in[8];
  const float* bp1  = (const float*)d_in[9];
  const float* Wp2  = (const float*)d_in[10];
  const float* bp2  = (const float*)d_in[11];
  const float* Wf1  = (const float*)d_in[12];
  const float* bf1  = (const float*)d_in[13];
  const float* Wf2  = (const float*)d_in[14];
  const float* bf2  = (const float*)d_in[15];
  const float* g1   = (const float*)d_in[16];
  const float* b1   = (const float*)d_in[17];
  const float* g2   = (const float*)d_in[18];
  const float* b2   = (const float*)d_in[19];

  float* out  = (float*)d_out;
  float* aout = out + (size_t)TOTPTS * DOUT;  // attn-weights output region (f32)

  // workspace layout (113 MB peak):
  //   [0, 1 MB)     final knn indices, uint16 (persists through attn)
  //   [1, 17 MB)    QOA bf16 (proj -> attn, aliased Q/out-rows)
  //   [17, 33 MB)   Kf bf16
  //   [26, 26.5)    phase: packed xyzw float4 (dead before proj writes Kf;
  //                 read by knn + pos kernels, which run before proj)
  //   [33, 49 MB)   Vf bf16
  //   [49, 113 MB)  posG bf16 [TOTPTS][KNN][64] (pos -> attn)
  unsigned short* knn  = (unsigned short*)d_ws;
  float4*         xyzw = (float4*)((char*)d_ws + (size_t)(26 << 20));
  bf16* QOA  = (bf16*)((char*)d_ws + (size_t)(1 << 20));
  bf16* Kf   = QOA + (size_t)TOTPTS * DOUT;
  bf16* Vf   = Kf  + (size_t)TOTPTS * DOUT;
  bf16* posG = (bf16*)((char*)d_ws + (size_t)(49 << 20));

  pack_kernel<<<TOTPTS / 256, 256, 0, stream>>>(xyz, xyzw);
  knn_wave_kernel<<<TOTPTS / 4, 256, 0, stream>>>(xyzw, knn);
  pos_kernel<<<TOTPTS / 4, 256, 0, stream>>>(xyzw, knn, Wp1, bp1, Wp2, bp2, posG);
  proj_kernel<<<TOTPTS / 8, 256, 0, stream>>>(feat, Wq, bq, Wk, bk, Wv, bv, g1, b1,
                                              QOA, Kf, Vf, /*skip->*/out);
  attn_kernel<<<TOTPTS, 256, 0, stream>>>(knn, QOA, Kf, Vf, posG, aout);
  ffn_kernel<<<TOTPTS / 8, 256, 0, stream>>>(QOA, Wf1, bf1, Wf2, bf2, g2, b2, out);
}

// Round 3
// 900.885 us; speedup vs baseline: 1.7189x; 1.0015x over previous
//
#include <hip/hip_runtime.h>
#include <hip/hip_bf16.h>
#include <math.h>

typedef __hip_bfloat16 bf16;

#define NBATCH 4
#define NPTS   8192
#define TOTPTS 32768
#define DIM    128
#define DOUT   256
#define KNN    16

__device__ __forceinline__ float b2f(bf16 x) { return __bfloat162float(x); }
__device__ __forceinline__ bf16 f2b(float x) { return __float2bfloat16(x); }

__device__ __forceinline__ float rsum32(float v) {
#pragma unroll
  for (int o = 16; o; o >>= 1) v += __shfl_down(v, o, 32);
  return v;
}

// ---------------------------------------------------------------------------
// Pack xyz -> (x, y, z, |p|^2) float4 (one coalesced 16B load per candidate).
// ---------------------------------------------------------------------------
__global__ __launch_bounds__(256) void pack_kernel(const float* __restrict__ xyz,
                                                   float4* __restrict__ xyzw) {
  const int p = blockIdx.x * 256 + threadIdx.x;
  const float x = xyz[3 * p], y = xyz[3 * p + 1], z = xyz[3 * p + 2];
  xyzw[p] = make_float4(x, y, z, x * x + y * y + z * z);
}

// ---------------------------------------------------------------------------
// 64-lane bitonic sort, ascending by lexicographic key (d, i). All keys
// distinct (indices unique) -> strict total order, deterministic.
// ---------------------------------------------------------------------------
__device__ __forceinline__ void sort64(float& d, int& i, const int lane) {
#pragma unroll
  for (int k = 2; k <= 64; k <<= 1) {
#pragma unroll
    for (int j = k >> 1; j >= 1; j >>= 1) {
      const float od = __shfl_xor(d, j, 64);
      const int   oi = __shfl_xor(i, j, 64);
      const bool takeMin = ((lane & k) == 0) == ((lane & j) == 0);
      const bool otherSmaller = (od < d) || (od == d && oi < i);
      if (takeMin == otherSmaller) { d = od; i = oi; }
    }
  }
}

// ---------------------------------------------------------------------------
// KNN v3 (round 3): append-then-rebuild. One wave per query, lane=candidate.
// Passing candidates are APPENDED to a per-wave LDS buffer via ballot+mbcnt
// (~5 wave-uniform ops per 64-group, no serial per-candidate loop). When the
// buffer would exceed 48, a 64-lane bitonic sort over {top16, buffer, +inf
// pad} rebuilds the top-16 and tightens the threshold (~4-5 rebuilds total
// vs ~116 serial inserts in v2). Lexicographic (d2, idx) selection with
// ascending-index append order == stable jax.lax.top_k tie semantics.
// Rare >48-passers-per-group case falls back to the proven serial insert.
// ---------------------------------------------------------------------------
__global__ __launch_bounds__(256) void knn_wave_kernel(
    const float4* __restrict__ xyzw, unsigned short* __restrict__ knn_out) {
  __shared__ float bufD[4][48];
  __shared__ int   bufI[4][48];
  const int wid  = threadIdx.x >> 6;
  const int lane = threadIdx.x & 63;
  const int q = blockIdx.x * 4 + wid;     // wave-uniform query id
  const int b = q >> 13;
  const float4 me = xyzw[q];
  const float qx = me.x, qy = me.y, qz = me.z, qs = me.w;
  const float4* cb = xyzw + (size_t)b * NPTS;

  float cur_d;                            // sorted list, lane = slot (0..15 live)
  int   cur_i;
  float tmax;                             // wave-uniform 16th-best distance
  int   base = 0;                         // buffered candidate count

  // seed: sort the first 64 candidates outright
  {
    const float4 t = cb[lane];
    cur_d = qs + t.w - 2.f * (qx * t.x + qy * t.y + qz * t.z);
    cur_i = lane;
    sort64(cur_d, cur_i, lane);
    tmax = __int_as_float(__builtin_amdgcn_readlane(__float_as_int(cur_d), 15));
  }

  auto rebuild = [&]() {                  // wave-uniform call sites only
    float sd; int si;
    if (lane < 16)            { sd = cur_d;               si = cur_i; }
    else if (lane - 16 < base){ sd = bufD[wid][lane - 16]; si = bufI[wid][lane - 16]; }
    else                      { sd = INFINITY;            si = 0x7fffffff; }
    sort64(sd, si, lane);
    cur_d = sd; cur_i = si;
    tmax = __int_as_float(__builtin_amdgcn_readlane(__float_as_int(sd), 15));
    base = 0;
  };

  for (int g = 64; g < NPTS; g += 64) {
    const float4 t = cb[g + lane];
    const float d2 = qs + t.w - 2.f * (qx * t.x + qy * t.y + qz * t.z);
    bool pass = d2 < tmax;
    unsigned long long mask = __ballot(pass);
    int cnt = __popcll(mask);
    bool doAppend = true;
    if (base + cnt > 48) {                // wave-uniform
      rebuild();
      pass = d2 < tmax;                   // re-screen vs tightened threshold
      mask = __ballot(pass);
      cnt = __popcll(mask);
      if (cnt > 48) {                     // ultra-rare adversarial case
        unsigned long long m = mask;
        while (m) {
          const int l = __builtin_ctzll(m);
          m &= m - 1;
          const float dl = __int_as_float(
              __builtin_amdgcn_readlane(__float_as_int(d2), l));
          if (dl < tmax) {
            const int il = g + l;
            const bool keep = cur_d <= dl;
            const float pd = __shfl_up(cur_d, 1, 64);
            const int   pi = __shfl_up(cur_i, 1, 64);
            const bool fromPrev = (lane > 0) && (pd > dl);
            cur_d = keep ? cur_d : (fromPrev ? pd : dl);
            cur_i = keep ? cur_i : (fromPrev ? pi : il);
            tmax = __int_as_float(
                __builtin_amdgcn_readlane(__float_as_int(cur_d), 15));
          }
        }
        doAppend = false;
      }
    }
    if (doAppend) {
      if (pass) {
        const int before = __builtin_amdgcn_mbcnt_hi(
            (unsigned)(mask >> 32),
            __builtin_amdgcn_mbcnt_lo((unsigned)mask, 0));
        bufD[wid][base + before] = d2;
        bufI[wid][base + before] = g + lane;
      }
      base += cnt;
    }
  }
  if (base > 0) rebuild();

  if (lane < 16)
    knn_out[(size_t)q * KNN + lane] = (unsigned short)cur_i;
}

// ---------------------------------------------------------------------------
// pos_kernel: the pos-MLP hoisted out of attn. Wave = point; lane = j/output
// dim. h1 (16 k-rows x 64) staged in LDS, pos phase reads h1 as wave-uniform
// broadcast ds_read_b128 (4 j's per op) so each Wp2 load is amortized over
// 16 rows. Runs BEFORE proj_kernel so the packed xyzw overlay (inside the
// future Kf region) is still alive. Output posG bf16[p][k][64].
// ---------------------------------------------------------------------------
__global__ __launch_bounds__(256) void pos_kernel(
    const float4* __restrict__ xyzw, const unsigned short* __restrict__ knn_in,
    const float* __restrict__ Wp1, const float* __restrict__ bp1,
    const float* __restrict__ Wp2, const float* __restrict__ bp2,
    bf16* __restrict__ posG) {
  __shared__ float h1S[4][16][64];        // 16 KB
  const int wid = threadIdx.x >> 6, lane = threadIdx.x & 63;
  const int p = blockIdx.x * 4 + wid;
  const int b = p >> 13, n = p & (NPTS - 1);
  const float4* cb = xyzw + (size_t)b * NPTS;
  const float4 me = cb[n];

  float rx = 0.f, ry = 0.f, rz = 0.f;
  if (lane < 16) {
    const int idx = knn_in[(size_t)p * KNN + lane];
    const float4 t = cb[idx];
    rx = t.x - me.x; ry = t.y - me.y; rz = t.z - me.z;
  }
  const float w0 = Wp1[lane], w1 = Wp1[64 + lane], w2 = Wp1[128 + lane];
  const float bb1 = bp1[lane], bb2 = bp2[lane];
#pragma unroll
  for (int k = 0; k < 16; k++) {
    const float r0 = __shfl(rx, k, 64);
    const float r1 = __shfl(ry, k, 64);
    const float r2 = __shfl(rz, k, 64);
    h1S[wid][k][lane] = fmaxf(bb1 + r0 * w0 + r1 * w1 + r2 * w2, 0.f);
  }
  __syncthreads();                        // cheap (4 waves); guards LDS RAW

  float acc[16];
#pragma unroll
  for (int k = 0; k < 16; k++) acc[k] = bb2;
  for (int jq = 0; jq < 16; jq++) {
    const float w2a = Wp2[(jq * 4 + 0) * 64 + lane];
    const float w2b = Wp2[(jq * 4 + 1) * 64 + lane];
    const float w2c = Wp2[(jq * 4 + 2) * 64 + lane];
    const float w2d = Wp2[(jq * 4 + 3) * 64 + lane];
#pragma unroll
    for (int k = 0; k < 16; k++) {
      const float4 h = *(const float4*)&h1S[wid][k][jq * 4];  // broadcast b128
      acc[k] += h.x * w2a + h.y * w2b + h.z * w2c + h.w * w2d;
    }
  }
#pragma unroll
  for (int k = 0; k < 16; k++)
    posG[((size_t)p * KNN + k) * 64 + lane] = f2b(acc[k]);
}

// ---------------------------------------------------------------------------
// Projections: per 8 rows compute LN1(features), then Q=f@Wq+bq, Kf=f@Wk+bk,
// Vf=f@Wv+bv (bf16 -> ws) and skip=LN1@Wq+bq (f32 -> d_out out-region).
// ---------------------------------------------------------------------------
__global__ __launch_bounds__(256) void proj_kernel(
    const float* __restrict__ feat,
    const float* __restrict__ Wq, const float* __restrict__ bq,
    const float* __restrict__ Wk, const float* __restrict__ bk,
    const float* __restrict__ Wv, const float* __restrict__ bv,
    const float* __restrict__ g1, const float* __restrict__ b1,
    bf16* __restrict__ Q, bf16* __restrict__ Kf, bf16* __restrict__ Vf,
    float* __restrict__ skip) {
  __shared__ float f[8][DIM];
  __shared__ float ln[8][DIM];
  __shared__ float mu8[8], rs8[8];
  const int tid = threadIdx.x;
  const size_t r0 = (size_t)blockIdx.x * 8;
  const float* src = feat + r0 * DIM;
#pragma unroll
  for (int i = 0; i < 4; i++) {
    const int idx = tid + i * 256;
    f[idx >> 7][idx & 127] = src[idx];
  }
  __syncthreads();
  const int r = tid >> 5, j = tid & 31;
  const float a0 = f[r][j], a1 = f[r][j + 32], a2 = f[r][j + 64], a3 = f[r][j + 96];
  float s = rsum32(a0 + a1 + a2 + a3);
  if (!j) mu8[r] = s * (1.f / 128.f);
  __syncthreads();
  const float mu = mu8[r];
  const float d0 = a0 - mu, d1 = a1 - mu, d2 = a2 - mu, d3 = a3 - mu;
  float ss = rsum32(d0 * d0 + d1 * d1 + d2 * d2 + d3 * d3);
  if (!j) rs8[r] = rsqrtf(ss * (1.f / 128.f) + 1e-5f);
  __syncthreads();
  const float rsd = rs8[r];
  ln[r][j]      = d0 * rsd * g1[j]      + b1[j];
  ln[r][j + 32] = d1 * rsd * g1[j + 32] + b1[j + 32];
  ln[r][j + 64] = d2 * rsd * g1[j + 64] + b1[j + 64];
  ln[r][j + 96] = d3 * rsd * g1[j + 96] + b1[j + 96];
  __syncthreads();
  float qa[8] = {}, ka[8] = {}, va[8] = {}, sa[8] = {};
  for (int d = 0; d < DIM; d += 4) {
    const float wq0 = Wq[(d + 0) * DOUT + tid], wq1 = Wq[(d + 1) * DOUT + tid];
    const float wq2 = Wq[(d + 2) * DOUT + tid], wq3 = Wq[(d + 3) * DOUT + tid];
    const float wk0 = Wk[(d + 0) * DOUT + tid], wk1 = Wk[(d + 1) * DOUT + tid];
    const float wk2 = Wk[(d + 2) * DOUT + tid], wk3 = Wk[(d + 3) * DOUT + tid];
    const float wv0 = Wv[(d + 0) * DOUT + tid], wv1 = Wv[(d + 1) * DOUT + tid];
    const float wv2 = Wv[(d + 2) * DOUT + tid], wv3 = Wv[(d + 3) * DOUT + tid];
#pragma unroll
    for (int rr = 0; rr < 8; rr++) {
      const float4 fv = *(const float4*)&f[rr][d];
      const float4 lv = *(const float4*)&ln[rr][d];
      qa[rr] += fv.x * wq0 + fv.y * wq1 + fv.z * wq2 + fv.w * wq3;
      ka[rr] += fv.x * wk0 + fv.y * wk1 + fv.z * wk2 + fv.w * wk3;
      va[rr] += fv.x * wv0 + fv.y * wv1 + fv.z * wv2 + fv.w * wv3;
      sa[rr] += lv.x * wq0 + lv.y * wq1 + lv.z * wq2 + lv.w * wq3;
    }
  }
  const float bqv = bq[tid], bkv = bk[tid], bvv = bv[tid];
#pragma unroll
  for (int rr = 0; rr < 8; rr++) {
    const size_t o = (r0 + rr) * DOUT + tid;
    Q[o]    = f2b(qa[rr] + bqv);
    Kf[o]   = f2b(ka[rr] + bkv);
    Vf[o]   = f2b(va[rr] + bvv);
    skip[o] = sa[rr] + bqv;
  }
}

// ---------------------------------------------------------------------------
// Attention v3: pos-MLP removed (precomputed posG, bf16). One block per
// point, wave = head, lane = dim. K/V gathered into registers, posr streamed
// coalesced. Logits via 16-accumulator __shfl_xor butterfly (lane-redundant
// softmax, barrier-free). 1 barrier total.
// ---------------------------------------------------------------------------
__global__ __launch_bounds__(256) void attn_kernel(
    const unsigned short* __restrict__ knn_in,
    bf16* __restrict__ QOA, const bf16* __restrict__ Kf, const bf16* __restrict__ Vf,
    const bf16* __restrict__ posG,
    float* __restrict__ AOUT) {
  __shared__ int nidxS[16];
  const int tid  = threadIdx.x;
  const int w    = tid >> 6;        // wave id = head
  const int lane = tid & 63;        // lane = dim within head
  const int p = blockIdx.x;
  const int b = p >> 13, n = p & (NPTS - 1);

  if (tid < 16) nidxS[tid] = knn_in[(size_t)p * KNN + tid];
  const float qreg = b2f(QOA[(size_t)p * DOUT + tid]);   // own row, pre-write
  __syncthreads();                  // nidxS ready

  // K/V gather + pos stream into registers
  float kreg[16], vreg[16], posr[16];
  const size_t rowbase = (size_t)b * NPTS;
  const bf16* pg = posG + (size_t)p * KNN * 64 + lane;
#pragma unroll
  for (int k = 0; k < 16; k++) {
    const size_t row = (rowbase + (size_t)nidxS[k]) * DOUT + tid;
    kreg[k] = b2f(Kf[row]);
    vreg[k] = b2f(Vf[row]);
    posr[k] = b2f(pg[k * 64]);
  }

  // logits: per-lane partials, butterfly reduce -> all lanes hold all 16
  float lg[16];
#pragma unroll
  for (int k = 0; k < 16; k++) lg[k] = qreg * (kreg[k] + posr[k]);
#pragma unroll
  for (int o = 32; o; o >>= 1) {
#pragma unroll
    for (int k = 0; k < 16; k++) lg[k] += __shfl_xor(lg[k], o, 64);
  }
  // softmax over k (lane-redundant, no sync)
  float m = -INFINITY;
#pragma unroll
  for (int k = 0; k < 16; k++) { lg[k] *= 0.125f; m = fmaxf(m, lg[k]); }
  float sum = 0.f;
#pragma unroll
  for (int k = 0; k < 16; k++) { lg[k] = expf(lg[k] - m); sum += lg[k]; }
  const float inv = 1.f / sum;
#pragma unroll
  for (int k = 0; k < 16; k++) lg[k] *= inv;
  // attn-weight store: lane l<16 writes a[l] (coalesced 64B per wave)
  float av = 0.f;
#pragma unroll
  for (int k = 0; k < 16; k++) if (lane == k) av = lg[k];
  if (lane < 16)
    AOUT[(((size_t)b * 4 + w) * NPTS + n) * KNN + lane] = av;
  // output: sum_k a[k] * (v[k] + pos[k][d]) -> overwrite own Q row
  float o = 0.f;
#pragma unroll
  for (int k = 0; k < 16; k++) o += lg[k] * (vreg[k] + posr[k]);
  QOA[(size_t)p * DOUT + tid] = f2b(o);
}

// ---------------------------------------------------------------------------
// FFN + LN2 + residual: per 8 rows: fc1=relu(x@Wf1+bf1), fc2=fc1@Wf2+bf2,
// out = LN2(fc2)*g2+b2 + skip. skip lives in d_out (f32; read, then
// overwritten by the same thread/element with the final f32 value).
// ---------------------------------------------------------------------------
__global__ __launch_bounds__(256) void ffn_kernel(
    const bf16* __restrict__ OA,
    const float* __restrict__ Wf1, const float* __restrict__ bf1,
    const float* __restrict__ Wf2, const float* __restrict__ bf2,
    const float* __restrict__ g2, const float* __restrict__ b2p,
    float* __restrict__ out) {
  __shared__ float x[8][DOUT];
  __shared__ float y[8][DOUT];
  __shared__ float mu8[8], rs8[8];
  const int tid = threadIdx.x;
  const size_t r0 = (size_t)blockIdx.x * 8;
  const bf16* src = OA + r0 * DOUT;
#pragma unroll
  for (int i = 0; i < 8; i++) x[i][tid] = b2f(src[i * DOUT + tid]);
  __syncthreads();
  float acc[8] = {};
  for (int d = 0; d < DOUT; d += 4) {
    const float w0 = Wf1[(d + 0) * DOUT + tid];
    const float w1 = Wf1[(d + 1) * DOUT + tid];
    const float w2 = Wf1[(d + 2) * DOUT + tid];
    const float w3 = Wf1[(d + 3) * DOUT + tid];
#pragma unroll
    for (int rr = 0; rr < 8; rr++) {
      const float4 v = *(const float4*)&x[rr][d];
      acc[rr] += v.x * w0 + v.y * w1 + v.z * w2 + v.w * w3;
    }
  }
  const float b1v = bf1[tid];
#pragma unroll
  for (int rr = 0; rr < 8; rr++) y[rr][tid] = fmaxf(acc[rr] + b1v, 0.f);
  __syncthreads();
  float acc2[8] = {};
  for (int d = 0; d < DOUT; d += 4) {
    const float w0 = Wf2[(d + 0) * DOUT + tid];
    const float w1 = Wf2[(d + 1) * DOUT + tid];
    const float w2 = Wf2[(d + 2) * DOUT + tid];
    const float w3 = Wf2[(d + 3) * DOUT + tid];
#pragma unroll
    for (int rr = 0; rr < 8; rr++) {
      const float4 v = *(const float4*)&y[rr][d];
      acc2[rr] += v.x * w0 + v.y * w1 + v.z * w2 + v.w * w3;
    }
  }
  const float b2v = bf2[tid];
#pragma unroll
  for (int rr = 0; rr < 8; rr++) x[rr][tid] = acc2[rr] + b2v;   // fc2 -> x
  __syncthreads();
  const int r = tid >> 5, j = tid & 31;
  float s = 0.f;
#pragma unroll
  for (int k2 = 0; k2 < 8; k2++) s += x[r][j + 32 * k2];
  s = rsum32(s);
  if (!j) mu8[r] = s * (1.f / 256.f);
  __syncthreads();
  const float mu = mu8[r];
  float ss = 0.f;
#pragma unroll
  for (int k2 = 0; k2 < 8; k2++) { const float dd = x[r][j + 32 * k2] - mu; ss += dd * dd; }
  ss = rsum32(ss);
  if (!j) rs8[r] = rsqrtf(ss * (1.f / 256.f) + 1e-5f);
  __syncthreads();
  const float gv = g2[tid], bbv = b2p[tid];
#pragma unroll
  for (int rr = 0; rr < 8; rr++) {
    const size_t o = (r0 + rr) * DOUT + tid;
    const float sk = out[o];        // skip stored here by proj_kernel (f32)
    out[o] = (x[rr][tid] - mu8[rr]) * rs8[rr] * gv + bbv + sk;
  }
}

extern "C" void kernel_launch(void* const* d_in, const int* in_sizes, int n_in,
                              void* d_out, int out_size, void* d_ws, size_t ws_size,
                              hipStream_t stream) {
  const float* xyz  = (const float*)d_in[0];
  const float* feat = (const float*)d_in[1];
  const float* Wq   = (const float*)d_in[2];
  const float* bq   = (const float*)d_in[3];
  const float* Wk   = (const float*)d_in[4];
  const float* bk   = (const float*)d_in[5];
  const float* Wv   = (const float*)d_in[6];
  const float* bv   = (const float*)d_in[7];
  const float* Wp1  = (const float*)d_in[8];
  const float* bp1  = (const float*)d_in[9];
  const float* Wp2  = (const float*)d_in[10];
  const float* bp2  = (const float*)d_in[11];
  const float* Wf1  = (const float*)d_in[12];
  const float* bf1  = (const float*)d_in[13];
  const float* Wf2  = (const float*)d_in[14];
  const float* bf2  = (const float*)d_in[15];
  const float* g1   = (const float*)d_in[16];
  const float* b1   = (const float*)d_in[17];
  const float* g2   = (const float*)d_in[18];
  const float* b2   = (const float*)d_in[19];

  float* out  = (float*)d_out;
  float* aout = out + (size_t)TOTPTS * DOUT;  // attn-weights output region (f32)

  // workspace layout (113 MB peak):
  //   [0, 1 MB)     final knn indices, uint16 (persists through attn)
  //   [1, 17 MB)    QOA bf16 (proj -> attn, aliased Q/out-rows)
  //   [17, 33 MB)   Kf bf16
  //   [26, 26.5)    phase: packed xyzw float4 (dead before proj writes Kf;
  //                 read by knn + pos kernels, which run before proj)
  //   [33, 49 MB)   Vf bf16
  //   [49, 113 MB)  posG bf16 [TOTPTS][KNN][64] (pos -> attn)
  unsigned short* knn  = (unsigned short*)d_ws;
  float4*         xyzw = (float4*)((char*)d_ws + (size_t)(26 << 20));
  bf16* QOA  = (bf16*)((char*)d_ws + (size_t)(1 << 20));
  bf16* Kf   = QOA + (size_t)TOTPTS * DOUT;
  bf16* Vf   = Kf  + (size_t)TOTPTS * DOUT;
  bf16* posG = (bf16*)((char*)d_ws + (size_t)(49 << 20));

  pack_kernel<<<TOTPTS / 256, 256, 0, stream>>>(xyz, xyzw);
  knn_wave_kernel<<<TOTPTS / 4, 256, 0, stream>>>(xyzw, knn);
  pos_kernel<<<TOTPTS / 4, 256, 0, stream>>>(xyzw, knn, Wp1, bp1, Wp2, bp2, posG);
  proj_kernel<<<TOTPTS / 8, 256, 0, stream>>>(feat, Wq, bq, Wk, bk, Wv, bv, g1, b1,
                                              QOA, Kf, Vf, /*skip->*/out);
  attn_kernel<<<TOTPTS, 256, 0, stream>>>(knn, QOA, Kf, Vf, posG, aout);
  ffn_kernel<<<TOTPTS / 8, 256, 0, stream>>>(QOA, Wf1, bf1, Wf2, bf2, g2, b2, out);
}

// Round 4
// 852.982 us; speedup vs baseline: 1.8155x; 1.0562x over previous
//
#include <hip/hip_runtime.h>
#include <hip/hip_bf16.h>
#include <math.h>

typedef __hip_bfloat16 bf16;

#define NBATCH 4
#define NPTS   8192
#define TOTPTS 32768
#define DIM    128
#define DOUT   256
#define KNN    16

__device__ __forceinline__ float b2f(bf16 x) { return __bfloat162float(x); }
__device__ __forceinline__ bf16 f2b(float x) { return __float2bfloat16(x); }

__device__ __forceinline__ float rsum32(float v) {
#pragma unroll
  for (int o = 16; o; o >>= 1) v += __shfl_down(v, o, 32);
  return v;
}

// ---------------------------------------------------------------------------
// Pack xyz -> (x, y, z, |p|^2) float4 (one coalesced 16B load per candidate).
// ---------------------------------------------------------------------------
__global__ __launch_bounds__(256) void pack_kernel(const float* __restrict__ xyz,
                                                   float4* __restrict__ xyzw) {
  const int p = blockIdx.x * 256 + threadIdx.x;
  const float x = xyz[3 * p], y = xyz[3 * p + 1], z = xyz[3 * p + 2];
  xyzw[p] = make_float4(x, y, z, x * x + y * y + z * z);
}

// ---------------------------------------------------------------------------
// Segmented insert for KNN v4: the top-16 of query S lives in lanes
// [16S, 16S+15] (slot = lane&15, ascending). Serial over passing candidates
// (v2-proven scheme); width-16 shfl_up keeps the shift inside the segment;
// non-segment lanes are masked by the (seg==S) predicate. Ascending index
// order + (bd <= dl) keep-condition == stable jax.lax.top_k tie semantics.
// ---------------------------------------------------------------------------
template <int S>
__device__ __forceinline__ void ins16(float d2, int g, int lane, int seg,
                                      float& bd, int& bi, float& tmax) {
  unsigned long long mask = __ballot(d2 < tmax);
  while (mask) {                          // wave-uniform loop
    const int l = __builtin_ctzll(mask);
    mask &= mask - 1;
    const float dl = __int_as_float(
        __builtin_amdgcn_readlane(__float_as_int(d2), l));
    if (dl < tmax) {                      // re-check vs tightened threshold
      const int il = g + l;
      const bool keep = bd <= dl;
      const float pd = __shfl_up(bd, 1, 16);    // segmented shift
      const int   pi = __shfl_up(bi, 1, 16);
      const bool fromPrev = ((lane & 15) > 0) && (pd > dl);
      const float nbd = keep ? bd : (fromPrev ? pd : dl);
      const int   nbi = keep ? bi : (fromPrev ? pi : il);
      bd = (seg == S) ? nbd : bd;         // only segment S updates
      bi = (seg == S) ? nbi : bi;
      tmax = __int_as_float(
          __builtin_amdgcn_readlane(__float_as_int(bd), S * 16 + 15));
    }
  }
}

// ---------------------------------------------------------------------------
// KNN v4 (round 4): 4 queries per wave. Each candidate float4 load feeds 4
// distance computations (scan iterations & L2 traffic per query /4 vs v2's
// 18 TB/s = 52% of L2 ceiling). Top-16 lists segmented across the 4
// 16-lane groups; insert = v2's serial scheme (v3's bitonic rebuild was
// neutral: it swapped VALU work for DS-latency chains). Final store: each
// lane writes slot (lane&15) of query (q0+seg) -> one coalesced 128B store.
// ---------------------------------------------------------------------------
__global__ __launch_bounds__(256) void knn_wave_kernel(
    const float4* __restrict__ xyzw, unsigned short* __restrict__ knn_out) {
  const int wid  = threadIdx.x >> 6;
  const int lane = threadIdx.x & 63;
  const int seg  = lane >> 4;             // which query's list this lane holds
  const int q0 = (blockIdx.x * 4 + wid) * 4;   // 4 consecutive queries
  const int b = q0 >> 13;                 // same batch for all 4 (q0 % 4 == 0)
  const float4* cb = xyzw + (size_t)b * NPTS;

  const float4 mA = xyzw[q0 + 0];
  const float4 mB = xyzw[q0 + 1];
  const float4 mC = xyzw[q0 + 2];
  const float4 mD = xyzw[q0 + 3];

  float bd = INFINITY;                    // slot (lane&15) of query (q0+seg)
  int   bi = 0x7fff;
  float tA = INFINITY, tB = INFINITY, tC = INFINITY, tD = INFINITY;

  for (int g = 0; g < NPTS; g += 64) {
    const float4 t = cb[g + lane];
    const float dA = mA.w + t.w - 2.f * (mA.x * t.x + mA.y * t.y + mA.z * t.z);
    const float dB = mB.w + t.w - 2.f * (mB.x * t.x + mB.y * t.y + mB.z * t.z);
    const float dC = mC.w + t.w - 2.f * (mC.x * t.x + mC.y * t.y + mC.z * t.z);
    const float dD = mD.w + t.w - 2.f * (mD.x * t.x + mD.y * t.y + mD.z * t.z);
    ins16<0>(dA, g, lane, seg, bd, bi, tA);
    ins16<1>(dB, g, lane, seg, bd, bi, tB);
    ins16<2>(dC, g, lane, seg, bd, bi, tC);
    ins16<3>(dD, g, lane, seg, bd, bi, tD);
  }
  // lane holds slot (lane&15) of query (q0+seg): contiguous 64 u16 = 128B
  knn_out[(size_t)q0 * KNN + lane] = (unsigned short)bi;
}

// ---------------------------------------------------------------------------
// pos_kernel: the pos-MLP hoisted out of attn. Wave = point; lane = j/output
// dim. h1 (16 k-rows x 64) staged in LDS, pos phase reads h1 as wave-uniform
// broadcast ds_read_b128 (4 j's per op) so each Wp2 load is amortized over
// 16 rows. Runs BEFORE proj_kernel so the packed xyzw overlay (inside the
// future Kf region) is still alive. Output posG bf16[p][k][64].
// ---------------------------------------------------------------------------
__global__ __launch_bounds__(256) void pos_kernel(
    const float4* __restrict__ xyzw, const unsigned short* __restrict__ knn_in,
    const float* __restrict__ Wp1, const float* __restrict__ bp1,
    const float* __restrict__ Wp2, const float* __restrict__ bp2,
    bf16* __restrict__ posG) {
  __shared__ float h1S[4][16][64];        // 16 KB
  const int wid = threadIdx.x >> 6, lane = threadIdx.x & 63;
  const int p = blockIdx.x * 4 + wid;
  const int b = p >> 13, n = p & (NPTS - 1);
  const float4* cb = xyzw + (size_t)b * NPTS;
  const float4 me = cb[n];

  float rx = 0.f, ry = 0.f, rz = 0.f;
  if (lane < 16) {
    const int idx = knn_in[(size_t)p * KNN + lane];
    const float4 t = cb[idx];
    rx = t.x - me.x; ry = t.y - me.y; rz = t.z - me.z;
  }
  const float w0 = Wp1[lane], w1 = Wp1[64 + lane], w2 = Wp1[128 + lane];
  const float bb1 = bp1[lane], bb2 = bp2[lane];
#pragma unroll
  for (int k = 0; k < 16; k++) {
    const float r0 = __shfl(rx, k, 64);
    const float r1 = __shfl(ry, k, 64);
    const float r2 = __shfl(rz, k, 64);
    h1S[wid][k][lane] = fmaxf(bb1 + r0 * w0 + r1 * w1 + r2 * w2, 0.f);
  }
  __syncthreads();                        // cheap (4 waves); guards LDS RAW

  float acc[16];
#pragma unroll
  for (int k = 0; k < 16; k++) acc[k] = bb2;
  for (int jq = 0; jq < 16; jq++) {
    const float w2a = Wp2[(jq * 4 + 0) * 64 + lane];
    const float w2b = Wp2[(jq * 4 + 1) * 64 + lane];
    const float w2c = Wp2[(jq * 4 + 2) * 64 + lane];
    const float w2d = Wp2[(jq * 4 + 3) * 64 + lane];
#pragma unroll
    for (int k = 0; k < 16; k++) {
      const float4 h = *(const float4*)&h1S[wid][k][jq * 4];  // broadcast b128
      acc[k] += h.x * w2a + h.y * w2b + h.z * w2c + h.w * w2d;
    }
  }
#pragma unroll
  for (int k = 0; k < 16; k++)
    posG[((size_t)p * KNN + k) * 64 + lane] = f2b(acc[k]);
}

// ---------------------------------------------------------------------------
// Projections: per 8 rows compute LN1(features), then Q=f@Wq+bq, Kf=f@Wk+bk,
// Vf=f@Wv+bv (bf16 -> ws) and skip=LN1@Wq+bq (f32 -> d_out out-region).
// ---------------------------------------------------------------------------
__global__ __launch_bounds__(256) void proj_kernel(
    const float* __restrict__ feat,
    const float* __restrict__ Wq, const float* __restrict__ bq,
    const float* __restrict__ Wk, const float* __restrict__ bk,
    const float* __restrict__ Wv, const float* __restrict__ bv,
    const float* __restrict__ g1, const float* __restrict__ b1,
    bf16* __restrict__ Q, bf16* __restrict__ Kf, bf16* __restrict__ Vf,
    float* __restrict__ skip) {
  __shared__ float f[8][DIM];
  __shared__ float ln[8][DIM];
  __shared__ float mu8[8], rs8[8];
  const int tid = threadIdx.x;
  const size_t r0 = (size_t)blockIdx.x * 8;
  const float* src = feat + r0 * DIM;
#pragma unroll
  for (int i = 0; i < 4; i++) {
    const int idx = tid + i * 256;
    f[idx >> 7][idx & 127] = src[idx];
  }
  __syncthreads();
  const int r = tid >> 5, j = tid & 31;
  const float a0 = f[r][j], a1 = f[r][j + 32], a2 = f[r][j + 64], a3 = f[r][j + 96];
  float s = rsum32(a0 + a1 + a2 + a3);
  if (!j) mu8[r] = s * (1.f / 128.f);
  __syncthreads();
  const float mu = mu8[r];
  const float d0 = a0 - mu, d1 = a1 - mu, d2 = a2 - mu, d3 = a3 - mu;
  float ss = rsum32(d0 * d0 + d1 * d1 + d2 * d2 + d3 * d3);
  if (!j) rs8[r] = rsqrtf(ss * (1.f / 128.f) + 1e-5f);
  __syncthreads();
  const float rsd = rs8[r];
  ln[r][j]      = d0 * rsd * g1[j]      + b1[j];
  ln[r][j + 32] = d1 * rsd * g1[j + 32] + b1[j + 32];
  ln[r][j + 64] = d2 * rsd * g1[j + 64] + b1[j + 64];
  ln[r][j + 96] = d3 * rsd * g1[j + 96] + b1[j + 96];
  __syncthreads();
  float qa[8] = {}, ka[8] = {}, va[8] = {}, sa[8] = {};
  for (int d = 0; d < DIM; d += 4) {
    const float wq0 = Wq[(d + 0) * DOUT + tid], wq1 = Wq[(d + 1) * DOUT + tid];
    const float wq2 = Wq[(d + 2) * DOUT + tid], wq3 = Wq[(d + 3) * DOUT + tid];
    const float wk0 = Wk[(d + 0) * DOUT + tid], wk1 = Wk[(d + 1) * DOUT + tid];
    const float wk2 = Wk[(d + 2) * DOUT + tid], wk3 = Wk[(d + 3) * DOUT + tid];
    const float wv0 = Wv[(d + 0) * DOUT + tid], wv1 = Wv[(d + 1) * DOUT + tid];
    const float wv2 = Wv[(d + 2) * DOUT + tid], wv3 = Wv[(d + 3) * DOUT + tid];
#pragma unroll
    for (int rr = 0; rr < 8; rr++) {
      const float4 fv = *(const float4*)&f[rr][d];
      const float4 lv = *(const float4*)&ln[rr][d];
      qa[rr] += fv.x * wq0 + fv.y * wq1 + fv.z * wq2 + fv.w * wq3;
      ka[rr] += fv.x * wk0 + fv.y * wk1 + fv.z * wk2 + fv.w * wk3;
      va[rr] += fv.x * wv0 + fv.y * wv1 + fv.z * wv2 + fv.w * wv3;
      sa[rr] += lv.x * wq0 + lv.y * wq1 + lv.z * wq2 + lv.w * wq3;
    }
  }
  const float bqv = bq[tid], bkv = bk[tid], bvv = bv[tid];
#pragma unroll
  for (int rr = 0; rr < 8; rr++) {
    const size_t o = (r0 + rr) * DOUT + tid;
    Q[o]    = f2b(qa[rr] + bqv);
    Kf[o]   = f2b(ka[rr] + bkv);
    Vf[o]   = f2b(va[rr] + bvv);
    skip[o] = sa[rr] + bqv;
  }
}

// ---------------------------------------------------------------------------
// Attention v3: pos-MLP removed (precomputed posG, bf16). One block per
// point, wave = head, lane = dim. K/V gathered into registers, posr streamed
// coalesced. Logits via 16-accumulator __shfl_xor butterfly (lane-redundant
// softmax, barrier-free). 1 barrier total.
// ---------------------------------------------------------------------------
__global__ __launch_bounds__(256) void attn_kernel(
    const unsigned short* __restrict__ knn_in,
    bf16* __restrict__ QOA, const bf16* __restrict__ Kf, const bf16* __restrict__ Vf,
    const bf16* __restrict__ posG,
    float* __restrict__ AOUT) {
  __shared__ int nidxS[16];
  const int tid  = threadIdx.x;
  const int w    = tid >> 6;        // wave id = head
  const int lane = tid & 63;        // lane = dim within head
  const int p = blockIdx.x;
  const int b = p >> 13, n = p & (NPTS - 1);

  if (tid < 16) nidxS[tid] = knn_in[(size_t)p * KNN + tid];
  const float qreg = b2f(QOA[(size_t)p * DOUT + tid]);   // own row, pre-write
  __syncthreads();                  // nidxS ready

  // K/V gather + pos stream into registers
  float kreg[16], vreg[16], posr[16];
  const size_t rowbase = (size_t)b * NPTS;
  const bf16* pg = posG + (size_t)p * KNN * 64 + lane;
#pragma unroll
  for (int k = 0; k < 16; k++) {
    const size_t row = (rowbase + (size_t)nidxS[k]) * DOUT + tid;
    kreg[k] = b2f(Kf[row]);
    vreg[k] = b2f(Vf[row]);
    posr[k] = b2f(pg[k * 64]);
  }

  // logits: per-lane partials, butterfly reduce -> all lanes hold all 16
  float lg[16];
#pragma unroll
  for (int k = 0; k < 16; k++) lg[k] = qreg * (kreg[k] + posr[k]);
#pragma unroll
  for (int o = 32; o; o >>= 1) {
#pragma unroll
    for (int k = 0; k < 16; k++) lg[k] += __shfl_xor(lg[k], o, 64);
  }
  // softmax over k (lane-redundant, no sync)
  float m = -INFINITY;
#pragma unroll
  for (int k = 0; k < 16; k++) { lg[k] *= 0.125f; m = fmaxf(m, lg[k]); }
  float sum = 0.f;
#pragma unroll
  for (int k = 0; k < 16; k++) { lg[k] = expf(lg[k] - m); sum += lg[k]; }
  const float inv = 1.f / sum;
#pragma unroll
  for (int k = 0; k < 16; k++) lg[k] *= inv;
  // attn-weight store: lane l<16 writes a[l] (coalesced 64B per wave)
  float av = 0.f;
#pragma unroll
  for (int k = 0; k < 16; k++) if (lane == k) av = lg[k];
  if (lane < 16)
    AOUT[(((size_t)b * 4 + w) * NPTS + n) * KNN + lane] = av;
  // output: sum_k a[k] * (v[k] + pos[k][d]) -> overwrite own Q row
  float o = 0.f;
#pragma unroll
  for (int k = 0; k < 16; k++) o += lg[k] * (vreg[k] + posr[k]);
  QOA[(size_t)p * DOUT + tid] = f2b(o);
}

// ---------------------------------------------------------------------------
// FFN + LN2 + residual, v2 (round 4): 16 rows per block (was 8). Halves the
// Wf1/Wf2 L2 re-read traffic (2.1 GB -> 1.05 GB) and doubles the FMA:ds_read
// ratio in the GEMM phases. LN2 reworked to 16 threads/row (width-16 shfl
// reduce). skip lives in d_out (f32; read, then overwritten by the same
// thread/element with the final f32 value).
// ---------------------------------------------------------------------------
#define FR 16
__global__ __launch_bounds__(256) void ffn_kernel(
    const bf16* __restrict__ OA,
    const float* __restrict__ Wf1, const float* __restrict__ bf1,
    const float* __restrict__ Wf2, const float* __restrict__ bf2,
    const float* __restrict__ g2, const float* __restrict__ b2p,
    float* __restrict__ out) {
  __shared__ float x[FR][DOUT];
  __shared__ float y[FR][DOUT];
  __shared__ float mu16[FR], rs16[FR];
  const int tid = threadIdx.x;
  const size_t r0 = (size_t)blockIdx.x * FR;
  const bf16* src = OA + r0 * DOUT;
#pragma unroll
  for (int i = 0; i < FR; i++) x[i][tid] = b2f(src[i * DOUT + tid]);
  __syncthreads();
  float acc[FR] = {};
  for (int d = 0; d < DOUT; d += 4) {
    const float w0 = Wf1[(d + 0) * DOUT + tid];
    const float w1 = Wf1[(d + 1) * DOUT + tid];
    const float w2 = Wf1[(d + 2) * DOUT + tid];
    const float w3 = Wf1[(d + 3) * DOUT + tid];
#pragma unroll
    for (int rr = 0; rr < FR; rr++) {
      const float4 v = *(const float4*)&x[rr][d];
      acc[rr] += v.x * w0 + v.y * w1 + v.z * w2 + v.w * w3;
    }
  }
  const float b1v = bf1[tid];
#pragma unroll
  for (int rr = 0; rr < FR; rr++) y[rr][tid] = fmaxf(acc[rr] + b1v, 0.f);
  __syncthreads();
  float acc2[FR] = {};
  for (int d = 0; d < DOUT; d += 4) {
    const float w0 = Wf2[(d + 0) * DOUT + tid];
    const float w1 = Wf2[(d + 1) * DOUT + tid];
    const float w2 = Wf2[(d + 2) * DOUT + tid];
    const float w3 = Wf2[(d + 3) * DOUT + tid];
#pragma unroll
    for (int rr = 0; rr < FR; rr++) {
      const float4 v = *(const float4*)&y[rr][d];
      acc2[rr] += v.x * w0 + v.y * w1 + v.z * w2 + v.w * w3;
    }
  }
  const float b2v = bf2[tid];
#pragma unroll
  for (int rr = 0; rr < FR; rr++) x[rr][tid] = acc2[rr] + b2v;   // fc2 -> x
  __syncthreads();
  // LN2 stats: 16 threads per row, width-16 shfl reduce
  const int r = tid >> 4, j = tid & 15;
  float s = 0.f;
#pragma unroll
  for (int k2 = 0; k2 < 16; k2++) s += x[r][j + 16 * k2];
#pragma unroll
  for (int o = 8; o; o >>= 1) s += __shfl_down(s, o, 16);
  if (!j) mu16[r] = s * (1.f / 256.f);
  __syncthreads();
  const float mu = mu16[r];
  float ss = 0.f;
#pragma unroll
  for (int k2 = 0; k2 < 16; k2++) { const float dd = x[r][j + 16 * k2] - mu; ss += dd * dd; }
#pragma unroll
  for (int o = 8; o; o >>= 1) ss += __shfl_down(ss, o, 16);
  if (!j) rs16[r] = rsqrtf(ss * (1.f / 256.f) + 1e-5f);
  __syncthreads();
  const float gv = g2[tid], bbv = b2p[tid];
#pragma unroll
  for (int rr = 0; rr < FR; rr++) {
    const size_t o = (r0 + rr) * DOUT + tid;
    const float sk = out[o];        // skip stored here by proj_kernel (f32)
    out[o] = (x[rr][tid] - mu16[rr]) * rs16[rr] * gv + bbv + sk;
  }
}

extern "C" void kernel_launch(void* const* d_in, const int* in_sizes, int n_in,
                              void* d_out, int out_size, void* d_ws, size_t ws_size,
                              hipStream_t stream) {
  const float* xyz  = (const float*)d_in[0];
  const float* feat = (const float*)d_in[1];
  const float* Wq   = (const float*)d_in[2];
  const float* bq   = (const float*)d_in[3];
  const float* Wk   = (const float*)d_in[4];
  const float* bk   = (const float*)d_in[5];
  const float* Wv   = (const float*)d_in[6];
  const float* bv   = (const float*)d_in[7];
  const float* Wp1  = (const float*)d_in[8];
  const float* bp1  = (const float*)d_in[9];
  const float* Wp2  = (const float*)d_in[10];
  const float* bp2  = (const float*)d_in[11];
  const float* Wf1  = (const float*)d_in[12];
  const float* bf1  = (const float*)d_in[13];
  const float* Wf2  = (const float*)d_in[14];
  const float* bf2  = (const float*)d_in[15];
  const float* g1   = (const float*)d_in[16];
  const float* b1   = (const float*)d_in[17];
  const float* g2   = (const float*)d_in[18];
  const float* b2   = (const float*)d_in[19];

  float* out  = (float*)d_out;
  float* aout = out + (size_t)TOTPTS * DOUT;  // attn-weights output region (f32)

  // workspace layout (113 MB peak):
  //   [0, 1 MB)     final knn indices, uint16 (persists through attn)
  //   [1, 17 MB)    QOA bf16 (proj -> attn, aliased Q/out-rows)
  //   [17, 33 MB)   Kf bf16
  //   [26, 26.5)    phase: packed xyzw float4 (dead before proj writes Kf;
  //                 read by knn + pos kernels, which run before proj)
  //   [33, 49 MB)   Vf bf16
  //   [49, 113 MB)  posG bf16 [TOTPTS][KNN][64] (pos -> attn)
  unsigned short* knn  = (unsigned short*)d_ws;
  float4*         xyzw = (float4*)((char*)d_ws + (size_t)(26 << 20));
  bf16* QOA  = (bf16*)((char*)d_ws + (size_t)(1 << 20));
  bf16* Kf   = QOA + (size_t)TOTPTS * DOUT;
  bf16* Vf   = Kf  + (size_t)TOTPTS * DOUT;
  bf16* posG = (bf16*)((char*)d_ws + (size_t)(49 << 20));

  pack_kernel<<<TOTPTS / 256, 256, 0, stream>>>(xyz, xyzw);
  knn_wave_kernel<<<TOTPTS / 16, 256, 0, stream>>>(xyzw, knn);
  pos_kernel<<<TOTPTS / 4, 256, 0, stream>>>(xyzw, knn, Wp1, bp1, Wp2, bp2, posG);
  proj_kernel<<<TOTPTS / 8, 256, 0, stream>>>(feat, Wq, bq, Wk, bk, Wv, bv, g1, b1,
                                              QOA, Kf, Vf, /*skip->*/out);
  attn_kernel<<<TOTPTS, 256, 0, stream>>>(knn, QOA, Kf, Vf, posG, aout);
  ffn_kernel<<<TOTPTS / FR, 256, 0, stream>>>(QOA, Wf1, bf1, Wf2, bf2, g2, b2, out);
}